// Round 1
// baseline (404.983 us; speedup 1.0000x reference)
//
#include <hip/hip_runtime.h>
#include <math.h>

#define N_NODES 50000
#define N_EDGES 800000
#define FDIM 128
#define NH 8
#define NC 32
#define D1 256      // NH*NC
#define NCLS 16
#define NGRP 64
#define NEG 0.2f
#define E_TOT (N_EDGES + N_NODES)

// ---------------- init: counts (self-loop = 1) + pooled accumulators ----------
__global__ void k_init(int* __restrict__ cnt, float* __restrict__ poolS,
                       float* __restrict__ poolC) {
    int i = blockIdx.x * blockDim.x + threadIdx.x;
    if (i < N_NODES) cnt[i] = 1;               // self loop
    if (i < NGRP * NCLS) poolS[i] = 0.f;
    if (i < NGRP) poolC[i] = 0.f;
}

// ---------------- GEMM1: xp1[N,256] = x[N,128] @ W1[128,256] ------------------
__global__ __launch_bounds__(256) void k_gemm1(const float* __restrict__ x,
                                               const float* __restrict__ W1,
                                               float* __restrict__ xp1) {
    __shared__ float xs[64][128];
    const int tid = threadIdx.x;
    const int base = blockIdx.x * 64;
    for (int idx = tid; idx < 64 * 32; idx += 256) {   // 2048 float4 loads
        int row = idx >> 5;
        int col4 = (idx & 31) << 2;
        float4 v = make_float4(0.f, 0.f, 0.f, 0.f);
        if (base + row < N_NODES)
            v = *(const float4*)(x + (size_t)(base + row) * FDIM + col4);
        *(float4*)(&xs[row][col4]) = v;
    }
    __syncthreads();
    const int c0 = (tid & 63) << 2;   // output column (x4)
    const int rg = tid >> 6;          // row group 0..3
    float4 acc[16];
#pragma unroll
    for (int r = 0; r < 16; ++r) acc[r] = make_float4(0.f, 0.f, 0.f, 0.f);
    for (int k0 = 0; k0 < FDIM; k0 += 8) {
        float4 w[8];
#pragma unroll
        for (int j = 0; j < 8; ++j)
            w[j] = *(const float4*)(W1 + (size_t)(k0 + j) * D1 + c0);
#pragma unroll
        for (int r = 0; r < 16; ++r) {
            const int row = rg * 16 + r;
            float4 a = acc[r];
#pragma unroll
            for (int j = 0; j < 8; ++j) {
                float xv = xs[row][k0 + j];
                a.x = fmaf(xv, w[j].x, a.x);
                a.y = fmaf(xv, w[j].y, a.y);
                a.z = fmaf(xv, w[j].z, a.z);
                a.w = fmaf(xv, w[j].w, a.w);
            }
            acc[r] = a;
        }
    }
#pragma unroll
    for (int r = 0; r < 16; ++r) {
        int row = base + rg * 16 + r;
        if (row < N_NODES)
            *(float4*)(xp1 + (size_t)row * D1 + c0) = acc[r];
    }
}

// ---------------- attention logits layer 1: al_s/al_d [N,8] -------------------
__global__ void k_al1(const float* __restrict__ xp1, const float* __restrict__ a1s,
                      const float* __restrict__ a1d, float* __restrict__ al1s,
                      float* __restrict__ al1d) {
    int t = blockIdx.x * blockDim.x + threadIdx.x;
    if (t >= N_NODES * NH) return;
    int h = t & 7;
    const float* xr = xp1 + (size_t)t * NC;     // t*32 == n*256 + h*32
    const float* as = a1s + h * NC;
    const float* ad = a1d + h * NC;
    float ss = 0.f, dd = 0.f;
#pragma unroll
    for (int c = 0; c < NC; c += 4) {
        float4 v = *(const float4*)(xr + c);
        float4 s4 = *(const float4*)(as + c);
        float4 d4 = *(const float4*)(ad + c);
        ss += v.x * s4.x + v.y * s4.y + v.z * s4.z + v.w * s4.w;
        dd += v.x * d4.x + v.y * d4.y + v.z * d4.z + v.w * d4.w;
    }
    al1s[t] = ss;
    al1d[t] = dd;
}

// ---------------- CSR build ---------------------------------------------------
__global__ void k_hist(const int* __restrict__ ei, int* __restrict__ cnt) {
    int e = blockIdx.x * blockDim.x + threadIdx.x;
    if (e >= N_EDGES) return;
    atomicAdd(&cnt[ei[N_EDGES + e]], 1);
}

__global__ void k_scan1(const int* __restrict__ cnt, int* __restrict__ rowptr,
                        int* __restrict__ bsums) {
    __shared__ int sh[256];
    int i = blockIdx.x * 256 + threadIdx.x;
    int v = (i < N_NODES) ? cnt[i] : 0;
    sh[threadIdx.x] = v;
    __syncthreads();
    for (int d = 1; d < 256; d <<= 1) {
        int t = (threadIdx.x >= d) ? sh[threadIdx.x - d] : 0;
        __syncthreads();
        sh[threadIdx.x] += t;
        __syncthreads();
    }
    if (i < N_NODES) rowptr[i] = sh[threadIdx.x] - v;   // exclusive
    if (threadIdx.x == 255) bsums[blockIdx.x] = sh[255];
}

__global__ void k_scan2(int* __restrict__ bsums, int nb) {
    __shared__ int sh[256];
    int v = (threadIdx.x < nb) ? bsums[threadIdx.x] : 0;
    sh[threadIdx.x] = v;
    __syncthreads();
    for (int d = 1; d < 256; d <<= 1) {
        int t = (threadIdx.x >= d) ? sh[threadIdx.x - d] : 0;
        __syncthreads();
        sh[threadIdx.x] += t;
        __syncthreads();
    }
    bsums[threadIdx.x] = sh[threadIdx.x] - v;           // exclusive
}

__global__ void k_scan3(int* __restrict__ rowptr, const int* __restrict__ bsums,
                        int* __restrict__ cursor) {
    int i = blockIdx.x * 256 + threadIdx.x;
    if (i < N_NODES) {
        int r = rowptr[i] + bsums[blockIdx.x];
        rowptr[i] = r;
        cursor[i] = r;
    }
}

__global__ void k_scatter(const int* __restrict__ ei, int* __restrict__ cursor,
                          int* __restrict__ esrc) {
    int e = blockIdx.x * blockDim.x + threadIdx.x;
    if (e >= E_TOT) return;
    int s, d;
    if (e < N_EDGES) { s = ei[e]; d = ei[N_EDGES + e]; }
    else { s = d = e - N_EDGES; }
    int pos = atomicAdd(&cursor[d], 1);
    esrc[pos] = s;
}

// ---------------- attention layer 1 (wave per dst node) -----------------------
__global__ __launch_bounds__(256) void k_att1(
    const float* __restrict__ xp1, const float* __restrict__ al1s,
    const float* __restrict__ al1d, const float* __restrict__ b1,
    const int* __restrict__ rowptr, const int* __restrict__ cnt,
    const int* __restrict__ esrc, float* __restrict__ h1out) {
    int wave = threadIdx.x >> 6;
    int lane = threadIdx.x & 63;
    int n = blockIdx.x * 4 + wave;
    if (n >= N_NODES) return;
    int start = rowptr[n];
    int deg = cnt[n];
    int h = lane & 7;
    int eg = lane >> 3;                    // 8 edges x 8 heads
    float ald = al1d[n * NH + h];
    float m = -1e30f;
    for (int j = eg; j < deg; j += 8) {
        int s = esrc[start + j];
        float v = al1s[s * NH + h] + ald;
        v = v > 0.f ? v : NEG * v;
        m = fmaxf(m, v);
    }
    for (int msk = 8; msk < 64; msk <<= 1) m = fmaxf(m, __shfl_xor(m, msk));
    float den = 0.f;
    for (int j = eg; j < deg; j += 8) {
        int s = esrc[start + j];
        float v = al1s[s * NH + h] + ald;
        v = v > 0.f ? v : NEG * v;
        den += expf(v - m);
    }
    for (int msk = 8; msk < 64; msk <<= 1) den += __shfl_xor(den, msk);
    // redistribute: lane owns channels [lane*4, lane*4+4) -> head h2 = lane>>3
    int h2 = lane >> 3;
    float m2 = __shfl(m, h2);
    float den2 = __shfl(den, h2);
    float ald2 = al1d[n * NH + h2];
    float rden = 1.f / den2;
    int cbase = lane << 2;
    float4 acc = make_float4(0.f, 0.f, 0.f, 0.f);
    for (int j = 0; j < deg; ++j) {
        int s = esrc[start + j];
        float v = al1s[s * NH + h2] + ald2;
        v = v > 0.f ? v : NEG * v;
        float alpha = expf(v - m2) * rden;
        float4 xv = *(const float4*)(xp1 + (size_t)s * D1 + cbase);
        acc.x = fmaf(alpha, xv.x, acc.x);
        acc.y = fmaf(alpha, xv.y, acc.y);
        acc.z = fmaf(alpha, xv.z, acc.z);
        acc.w = fmaf(alpha, xv.w, acc.w);
    }
    float4 bb = *(const float4*)(b1 + cbase);
    acc.x += bb.x; acc.y += bb.y; acc.z += bb.z; acc.w += bb.w;
    acc.x = acc.x > 0.f ? acc.x : expm1f(acc.x);   // ELU fused
    acc.y = acc.y > 0.f ? acc.y : expm1f(acc.y);
    acc.z = acc.z > 0.f ? acc.z : expm1f(acc.z);
    acc.w = acc.w > 0.f ? acc.w : expm1f(acc.w);
    *(float4*)(h1out + (size_t)n * D1 + cbase) = acc;
}

// ---------------- GEMM2 + al2 epilogue ----------------------------------------
__global__ __launch_bounds__(256) void k_gemm2(
    const float* __restrict__ h1, const float* __restrict__ W2,
    const float* __restrict__ a2s, const float* __restrict__ a2d,
    float* __restrict__ xp2, float* __restrict__ al2s, float* __restrict__ al2d) {
    __shared__ float w2s[D1 * NCLS];
    for (int i = threadIdx.x; i < D1 * NCLS; i += 256) w2s[i] = W2[i];
    __syncthreads();
    int n = blockIdx.x * 256 + threadIdx.x;
    if (n >= N_NODES) return;
    float4 acc[4];
#pragma unroll
    for (int q = 0; q < 4; ++q) acc[q] = make_float4(0.f, 0.f, 0.f, 0.f);
    const float* hr = h1 + (size_t)n * D1;
    for (int k0 = 0; k0 < D1; k0 += 4) {
        float4 hv = *(const float4*)(hr + k0);
        float hx[4] = {hv.x, hv.y, hv.z, hv.w};
#pragma unroll
        for (int j = 0; j < 4; ++j) {
#pragma unroll
            for (int q = 0; q < 4; ++q) {
                float4 w = *(const float4*)(&w2s[(k0 + j) * NCLS + q * 4]);
                acc[q].x = fmaf(hx[j], w.x, acc[q].x);
                acc[q].y = fmaf(hx[j], w.y, acc[q].y);
                acc[q].z = fmaf(hx[j], w.z, acc[q].z);
                acc[q].w = fmaf(hx[j], w.w, acc[q].w);
            }
        }
    }
    float ss = 0.f, dd = 0.f;
#pragma unroll
    for (int q = 0; q < 4; ++q) {
        *(float4*)(xp2 + (size_t)n * NCLS + q * 4) = acc[q];
        float4 s4 = *(const float4*)(a2s + q * 4);
        float4 d4 = *(const float4*)(a2d + q * 4);
        ss += acc[q].x * s4.x + acc[q].y * s4.y + acc[q].z * s4.z + acc[q].w * s4.w;
        dd += acc[q].x * d4.x + acc[q].y * d4.y + acc[q].z * d4.z + acc[q].w * d4.w;
    }
    al2s[n] = ss;
    al2d[n] = dd;
}

// ---------------- attention layer 2 (wave per dst node, 1 head) ---------------
__global__ __launch_bounds__(256) void k_att2(
    const float* __restrict__ xp2, const float* __restrict__ al2s,
    const float* __restrict__ al2d, const float* __restrict__ b2,
    const int* __restrict__ rowptr, const int* __restrict__ cnt,
    const int* __restrict__ esrc, float* __restrict__ out2) {
    int wave = threadIdx.x >> 6;
    int lane = threadIdx.x & 63;
    int n = blockIdx.x * 4 + wave;
    if (n >= N_NODES) return;
    int start = rowptr[n];
    int deg = cnt[n];
    float ald = al2d[n];
    float m = -1e30f;
    for (int j = lane; j < deg; j += 64) {
        float v = al2s[esrc[start + j]] + ald;
        v = v > 0.f ? v : NEG * v;
        m = fmaxf(m, v);
    }
    for (int msk = 1; msk < 64; msk <<= 1) m = fmaxf(m, __shfl_xor(m, msk));
    float den = 0.f;
    for (int j = lane; j < deg; j += 64) {
        float v = al2s[esrc[start + j]] + ald;
        v = v > 0.f ? v : NEG * v;
        den += expf(v - m);
    }
    for (int msk = 1; msk < 64; msk <<= 1) den += __shfl_xor(den, msk);
    float rden = 1.f / den;
    int c = lane & 15;
    int eg = lane >> 4;                   // 4 edges x 16 channels
    float acc = 0.f;
    for (int j = eg; j < deg; j += 4) {
        int s = esrc[start + j];
        float v = al2s[s] + ald;
        v = v > 0.f ? v : NEG * v;
        acc += expf(v - m) * rden * xp2[(size_t)s * NCLS + c];
    }
    acc += __shfl_xor(acc, 16);
    acc += __shfl_xor(acc, 32);
    if (lane < 16) out2[(size_t)n * NCLS + lane] = acc + b2[lane];
}

// ---------------- pooling ------------------------------------------------------
__global__ __launch_bounds__(256) void k_pool(
    const float* __restrict__ out2, const int* __restrict__ batch,
    float* __restrict__ poolS, float* __restrict__ poolC) {
    __shared__ float sacc[NGRP * NCLS];
    __shared__ float scnt[NGRP];
    for (int i = threadIdx.x; i < NGRP * NCLS; i += 256) sacc[i] = 0.f;
    if (threadIdx.x < NGRP) scnt[threadIdx.x] = 0.f;
    __syncthreads();
    int n = blockIdx.x * 256 + threadIdx.x;
    if (n < N_NODES) {
        int g = batch[n];
        atomicAdd(&scnt[g], 1.f);
#pragma unroll
        for (int cc = 0; cc < NCLS; ++cc)
            atomicAdd(&sacc[g * NCLS + cc], out2[(size_t)n * NCLS + cc]);
    }
    __syncthreads();
    for (int i = threadIdx.x; i < NGRP * NCLS; i += 256)
        if (sacc[i] != 0.f) atomicAdd(&poolS[i], sacc[i]);
    if (threadIdx.x < NGRP && scnt[threadIdx.x] != 0.f)
        atomicAdd(&poolC[threadIdx.x], scnt[threadIdx.x]);
}

__global__ void k_final(const float* __restrict__ poolS,
                        const float* __restrict__ poolC, float* __restrict__ out) {
    int g = threadIdx.x;
    if (g >= NGRP) return;
    float inv = 1.f / fmaxf(poolC[g], 1.f);
    float v[NCLS];
    float m = -1e30f;
#pragma unroll
    for (int c = 0; c < NCLS; ++c) {
        v[c] = poolS[g * NCLS + c] * inv;
        m = fmaxf(m, v[c]);
    }
    float s = 0.f;
#pragma unroll
    for (int c = 0; c < NCLS; ++c) s += expf(v[c] - m);
    float lse = m + logf(s);
#pragma unroll
    for (int c = 0; c < NCLS; ++c) out[g * NCLS + c] = v[c] - lse;
}

extern "C" void kernel_launch(void* const* d_in, const int* in_sizes, int n_in,
                              void* d_out, int out_size, void* d_ws, size_t ws_size,
                              hipStream_t stream) {
    const float* x    = (const float*)d_in[0];
    const int*   ei   = (const int*)d_in[1];
    const int*   batch = (const int*)d_in[2];
    const float* W1   = (const float*)d_in[3];
    const float* a1s  = (const float*)d_in[4];
    const float* a1d  = (const float*)d_in[5];
    const float* b1   = (const float*)d_in[6];
    const float* W2   = (const float*)d_in[7];
    const float* a2s  = (const float*)d_in[8];
    const float* a2d  = (const float*)d_in[9];
    const float* b2   = (const float*)d_in[10];
    float* out = (float*)d_out;

    float* f = (float*)d_ws;
    float* xp1   = f;  f += (size_t)N_NODES * D1;
    float* h1    = f;  f += (size_t)N_NODES * D1;
    float* al1s_ = f;  f += (size_t)N_NODES * NH;
    float* al1d_ = f;  f += (size_t)N_NODES * NH;
    float* xp2   = f;  f += (size_t)N_NODES * NCLS;
    float* al2s_ = f;  f += N_NODES;
    float* al2d_ = f;  f += N_NODES;
    float* out2  = f;  f += (size_t)N_NODES * NCLS;
    float* poolS = f;  f += NGRP * NCLS;
    float* poolC = f;  f += NGRP;
    int* cnt    = (int*)f;
    int* rowptr = cnt + N_NODES;
    int* cursor = rowptr + N_NODES;
    int* esrc   = cursor + N_NODES;
    int* bsums  = esrc + E_TOT;

    const int NB_N = (N_NODES + 255) / 256;   // 196

    k_init<<<NB_N, 256, 0, stream>>>(cnt, poolS, poolC);
    k_gemm1<<<(N_NODES + 63) / 64, 256, 0, stream>>>(x, W1, xp1);
    k_al1<<<(N_NODES * NH + 255) / 256, 256, 0, stream>>>(xp1, a1s, a1d, al1s_, al1d_);
    k_hist<<<(N_EDGES + 255) / 256, 256, 0, stream>>>(ei, cnt);
    k_scan1<<<NB_N, 256, 0, stream>>>(cnt, rowptr, bsums);
    k_scan2<<<1, 256, 0, stream>>>(bsums, NB_N);
    k_scan3<<<NB_N, 256, 0, stream>>>(rowptr, bsums, cursor);
    k_scatter<<<(E_TOT + 255) / 256, 256, 0, stream>>>(ei, cursor, esrc);
    k_att1<<<(N_NODES + 3) / 4, 256, 0, stream>>>(xp1, al1s_, al1d_, b1, rowptr, cnt, esrc, h1);
    k_gemm2<<<NB_N, 256, 0, stream>>>(h1, W2, a2s, a2d, xp2, al2s_, al2d_);
    k_att2<<<(N_NODES + 3) / 4, 256, 0, stream>>>(xp2, al2s_, al2d_, b2, rowptr, cnt, esrc, out2);
    k_pool<<<NB_N, 256, 0, stream>>>(out2, batch, poolS, poolC);
    k_final<<<1, 64, 0, stream>>>(poolS, poolC, out);
}

// Round 2
// 330.043 us; speedup vs baseline: 1.2271x; 1.2271x over previous
//
#include <hip/hip_runtime.h>
#include <math.h>

#define N_NODES 50000
#define N_EDGES 800000
#define FDIM 128
#define NH 8
#define NC 32
#define D1 256      // NH*NC
#define NCLS 16
#define NGRP 64
#define NEG 0.2f
#define E_TOT (N_EDGES + N_NODES)

typedef __attribute__((ext_vector_type(8))) unsigned short u16x8;
typedef __attribute__((ext_vector_type(4))) unsigned short u16x4;

static __device__ __forceinline__ float bf2f(unsigned short u) {
    return __uint_as_float(((unsigned int)u) << 16);
}
static __device__ __forceinline__ unsigned short f2bf(float f) {
    unsigned int b = __float_as_uint(f);
    return (unsigned short)((b + 0x7FFFu + ((b >> 16) & 1u)) >> 16);
}

// ---------------- init: counts (self-loop = 1) + pooled accumulators ----------
__global__ void k_init(int* __restrict__ cnt, float* __restrict__ poolS,
                       float* __restrict__ poolC) {
    int i = blockIdx.x * blockDim.x + threadIdx.x;
    if (i < N_NODES) cnt[i] = 1;               // self loop
    if (i < NGRP * NCLS) poolS[i] = 0.f;
    if (i < NGRP) poolC[i] = 0.f;
}

// -------- GEMM1: xp1b[N,256](bf16) = x@W1 ; fused al1 epilogue ---------------
__global__ __launch_bounds__(256) void k_gemm1(const float* __restrict__ x,
                                               const float* __restrict__ W1,
                                               const float* __restrict__ a1s,
                                               const float* __restrict__ a1d,
                                               unsigned short* __restrict__ xp1b,
                                               float* __restrict__ al1s,
                                               float* __restrict__ al1d) {
    __shared__ float xs[64][128];
    const int tid = threadIdx.x;
    const int base = blockIdx.x * 64;
    for (int idx = tid; idx < 64 * 32; idx += 256) {   // 2048 float4 loads
        int row = idx >> 5;
        int col4 = (idx & 31) << 2;
        float4 v = make_float4(0.f, 0.f, 0.f, 0.f);
        if (base + row < N_NODES)
            v = *(const float4*)(x + (size_t)(base + row) * FDIM + col4);
        *(float4*)(&xs[row][col4]) = v;
    }
    __syncthreads();
    const int lane = tid & 63;
    const int c0 = lane << 2;         // output column (x4)
    const int rg = tid >> 6;          // row group 0..3
    float4 acc[16];
#pragma unroll
    for (int r = 0; r < 16; ++r) acc[r] = make_float4(0.f, 0.f, 0.f, 0.f);
    for (int k0 = 0; k0 < FDIM; k0 += 8) {
        float4 w[8];
#pragma unroll
        for (int j = 0; j < 8; ++j)
            w[j] = *(const float4*)(W1 + (size_t)(k0 + j) * D1 + c0);
#pragma unroll
        for (int r = 0; r < 16; ++r) {
            const int row = rg * 16 + r;
            float4 a = acc[r];
#pragma unroll
            for (int j = 0; j < 8; ++j) {
                float xv = xs[row][k0 + j];
                a.x = fmaf(xv, w[j].x, a.x);
                a.y = fmaf(xv, w[j].y, a.y);
                a.z = fmaf(xv, w[j].z, a.z);
                a.w = fmaf(xv, w[j].w, a.w);
            }
            acc[r] = a;
        }
    }
    // epilogue: bf16 store + fused per-head attention logits
    const int h = lane >> 3;              // head owned by this 8-lane group
    const int cpos = (lane & 7) << 2;     // channel offset within head
    float4 as4 = *(const float4*)(a1s + h * NC + cpos);
    float4 ad4 = *(const float4*)(a1d + h * NC + cpos);
#pragma unroll
    for (int r = 0; r < 16; ++r) {
        int row = base + rg * 16 + r;
        float4 a = acc[r];
        if (row < N_NODES) {
            u16x4 pk = { f2bf(a.x), f2bf(a.y), f2bf(a.z), f2bf(a.w) };
            *(u16x4*)(xp1b + (size_t)row * D1 + c0) = pk;
        }
        float ss = a.x * as4.x + a.y * as4.y + a.z * as4.z + a.w * as4.w;
        float dd = a.x * ad4.x + a.y * ad4.y + a.z * ad4.z + a.w * ad4.w;
        ss += __shfl_xor(ss, 1); ss += __shfl_xor(ss, 2); ss += __shfl_xor(ss, 4);
        dd += __shfl_xor(dd, 1); dd += __shfl_xor(dd, 2); dd += __shfl_xor(dd, 4);
        if ((lane & 7) == 0 && row < N_NODES) {
            al1s[row * NH + h] = ss;
            al1d[row * NH + h] = dd;
        }
    }
}

// ---------------- CSR build ---------------------------------------------------
__global__ void k_hist(const int* __restrict__ ei, int* __restrict__ cnt) {
    int e = blockIdx.x * blockDim.x + threadIdx.x;
    if (e >= N_EDGES) return;
    atomicAdd(&cnt[ei[N_EDGES + e]], 1);
}

__global__ void k_scan1(const int* __restrict__ cnt, int* __restrict__ rowptr,
                        int* __restrict__ bsums) {
    __shared__ int sh[256];
    int i = blockIdx.x * 256 + threadIdx.x;
    int v = (i < N_NODES) ? cnt[i] : 0;
    sh[threadIdx.x] = v;
    __syncthreads();
    for (int d = 1; d < 256; d <<= 1) {
        int t = (threadIdx.x >= d) ? sh[threadIdx.x - d] : 0;
        __syncthreads();
        sh[threadIdx.x] += t;
        __syncthreads();
    }
    if (i < N_NODES) rowptr[i] = sh[threadIdx.x] - v;   // exclusive
    if (threadIdx.x == 255) bsums[blockIdx.x] = sh[255];
}

__global__ void k_scan2(int* __restrict__ bsums, int nb) {
    __shared__ int sh[256];
    int v = (threadIdx.x < nb) ? bsums[threadIdx.x] : 0;
    sh[threadIdx.x] = v;
    __syncthreads();
    for (int d = 1; d < 256; d <<= 1) {
        int t = (threadIdx.x >= d) ? sh[threadIdx.x - d] : 0;
        __syncthreads();
        sh[threadIdx.x] += t;
        __syncthreads();
    }
    bsums[threadIdx.x] = sh[threadIdx.x] - v;           // exclusive
}

__global__ void k_scan3(int* __restrict__ rowptr, const int* __restrict__ bsums,
                        int* __restrict__ cursor) {
    int i = blockIdx.x * 256 + threadIdx.x;
    if (i < N_NODES) {
        int r = rowptr[i] + bsums[blockIdx.x];
        rowptr[i] = r;
        cursor[i] = r;
    }
}

__global__ void k_scatter(const int* __restrict__ ei, int* __restrict__ cursor,
                          int* __restrict__ esrc) {
    int e = blockIdx.x * blockDim.x + threadIdx.x;
    if (e >= E_TOT) return;
    int s, d;
    if (e < N_EDGES) { s = ei[e]; d = ei[N_EDGES + e]; }
    else { s = d = e - N_EDGES; }
    int pos = atomicAdd(&cursor[d], 1);
    esrc[pos] = s;
}

// ---------------- attention layer 1 (wave per dst node) -----------------------
__global__ __launch_bounds__(256) void k_att1(
    const unsigned short* __restrict__ xp1b, const float* __restrict__ al1s,
    const float* __restrict__ al1d, const float* __restrict__ b1,
    const int* __restrict__ rowptr, const int* __restrict__ cnt,
    const int* __restrict__ esrc, unsigned short* __restrict__ h1b) {
    int wave = threadIdx.x >> 6;
    int lane = threadIdx.x & 63;
    int n = blockIdx.x * 4 + wave;
    if (n >= N_NODES) return;
    int start = rowptr[n];
    int deg = cnt[n];
    // pass 1: online softmax stats, 8 edges x 8 heads layout
    int h = lane & 7;
    int eg = lane >> 3;
    float ald = al1d[n * NH + h];
    float m = -1e30f, den = 0.f;
    for (int j = eg; j < deg; j += 8) {
        int s = esrc[start + j];
        float v = al1s[s * NH + h] + ald;
        v = v > 0.f ? v : NEG * v;
        if (v > m) { den = den * __expf(m - v) + 1.f; m = v; }
        else den += __expf(v - m);
    }
    for (int msk = 8; msk < 64; msk <<= 1) {
        float mo = __shfl_xor(m, msk), dn = __shfl_xor(den, msk);
        float nm = fmaxf(m, mo);
        den = den * __expf(m - nm) + dn * __expf(mo - nm);
        m = nm;
    }
    // pass 2: aggregation, 2 edges x (32 lanes x 8 bf16 channels)
    int eh = lane >> 5;
    int l = lane & 31;
    int h2 = l >> 2;
    float m2 = __shfl(m, h2);
    float rden = 1.f / __shfl(den, h2);
    float ald2 = al1d[n * NH + h2];
    const int cb = l << 3;
    float acc[8] = {0.f, 0.f, 0.f, 0.f, 0.f, 0.f, 0.f, 0.f};
    for (int j = eh; j < deg; j += 2) {
        int s = esrc[start + j];
        float v = al1s[s * NH + h2] + ald2;
        v = v > 0.f ? v : NEG * v;
        float alpha = __expf(v - m2) * rden;
        u16x8 xv = *(const u16x8*)(xp1b + (size_t)s * D1 + cb);
#pragma unroll
        for (int k = 0; k < 8; ++k) acc[k] = fmaf(alpha, bf2f(xv[k]), acc[k]);
    }
#pragma unroll
    for (int k = 0; k < 8; ++k) acc[k] += __shfl_xor(acc[k], 32);
    if (eh == 0) {
        u16x8 pk;
#pragma unroll
        for (int k = 0; k < 8; ++k) {
            float a = acc[k] + b1[cb + k];
            a = a > 0.f ? a : expm1f(a);   // ELU fused
            pk[k] = f2bf(a);
        }
        *(u16x8*)(h1b + (size_t)n * D1 + cb) = pk;
    }
}

// ---------------- GEMM2 (bf16 h1 in) + al2 epilogue ---------------------------
__global__ __launch_bounds__(256) void k_gemm2(
    const unsigned short* __restrict__ h1b, const float* __restrict__ W2,
    const float* __restrict__ a2s, const float* __restrict__ a2d,
    float* __restrict__ xp2, float* __restrict__ al2s, float* __restrict__ al2d) {
    __shared__ float w2s[D1 * NCLS];
    for (int i = threadIdx.x; i < D1 * NCLS; i += 256) w2s[i] = W2[i];
    __syncthreads();
    int n = blockIdx.x * 256 + threadIdx.x;
    if (n >= N_NODES) return;
    float4 acc[4];
#pragma unroll
    for (int q = 0; q < 4; ++q) acc[q] = make_float4(0.f, 0.f, 0.f, 0.f);
    const unsigned short* hr = h1b + (size_t)n * D1;
    for (int k0 = 0; k0 < D1; k0 += 8) {
        u16x8 hv = *(const u16x8*)(hr + k0);
#pragma unroll
        for (int j = 0; j < 8; ++j) {
            float hx = bf2f(hv[j]);
#pragma unroll
            for (int q = 0; q < 4; ++q) {
                float4 w = *(const float4*)(&w2s[(k0 + j) * NCLS + q * 4]);
                acc[q].x = fmaf(hx, w.x, acc[q].x);
                acc[q].y = fmaf(hx, w.y, acc[q].y);
                acc[q].z = fmaf(hx, w.z, acc[q].z);
                acc[q].w = fmaf(hx, w.w, acc[q].w);
            }
        }
    }
    float ss = 0.f, dd = 0.f;
#pragma unroll
    for (int q = 0; q < 4; ++q) {
        *(float4*)(xp2 + (size_t)n * NCLS + q * 4) = acc[q];
        float4 s4 = *(const float4*)(a2s + q * 4);
        float4 d4 = *(const float4*)(a2d + q * 4);
        ss += acc[q].x * s4.x + acc[q].y * s4.y + acc[q].z * s4.z + acc[q].w * s4.w;
        dd += acc[q].x * d4.x + acc[q].y * d4.y + acc[q].z * d4.z + acc[q].w * d4.w;
    }
    al2s[n] = ss;
    al2d[n] = dd;
}

// ---------------- attention layer 2 (wave per dst node, 1 head) ---------------
__global__ __launch_bounds__(256) void k_att2(
    const float* __restrict__ xp2, const float* __restrict__ al2s,
    const float* __restrict__ al2d, const float* __restrict__ b2,
    const int* __restrict__ rowptr, const int* __restrict__ cnt,
    const int* __restrict__ esrc, float* __restrict__ out2) {
    int wave = threadIdx.x >> 6;
    int lane = threadIdx.x & 63;
    int n = blockIdx.x * 4 + wave;
    if (n >= N_NODES) return;
    int start = rowptr[n];
    int deg = cnt[n];
    float ald = al2d[n];
    float m = -1e30f, den = 0.f;
    for (int j = lane; j < deg; j += 64) {
        float v = al2s[esrc[start + j]] + ald;
        v = v > 0.f ? v : NEG * v;
        if (v > m) { den = den * __expf(m - v) + 1.f; m = v; }
        else den += __expf(v - m);
    }
    for (int msk = 1; msk < 64; msk <<= 1) {
        float mo = __shfl_xor(m, msk), dn = __shfl_xor(den, msk);
        float nm = fmaxf(m, mo);
        den = den * __expf(m - nm) + dn * __expf(mo - nm);
        m = nm;
    }
    float rden = 1.f / den;
    int c = lane & 15;
    int eg = lane >> 4;                   // 4 edges x 16 channels
    float acc = 0.f;
    for (int j = eg; j < deg; j += 4) {
        int s = esrc[start + j];
        float v = al2s[s] + ald;
        v = v > 0.f ? v : NEG * v;
        acc += __expf(v - m) * rden * xp2[(size_t)s * NCLS + c];
    }
    acc += __shfl_xor(acc, 16);
    acc += __shfl_xor(acc, 32);
    if (lane < 16) out2[(size_t)n * NCLS + lane] = acc + b2[lane];
}

// ---------------- pooling ------------------------------------------------------
__global__ __launch_bounds__(256) void k_pool(
    const float* __restrict__ out2, const int* __restrict__ batch,
    float* __restrict__ poolS, float* __restrict__ poolC) {
    __shared__ float sacc[NGRP * NCLS];
    __shared__ float scnt[NGRP];
    for (int i = threadIdx.x; i < NGRP * NCLS; i += 256) sacc[i] = 0.f;
    if (threadIdx.x < NGRP) scnt[threadIdx.x] = 0.f;
    __syncthreads();
    int n = blockIdx.x * 256 + threadIdx.x;
    if (n < N_NODES) {
        int g = batch[n];
        atomicAdd(&scnt[g], 1.f);
#pragma unroll
        for (int cc = 0; cc < NCLS; ++cc)
            atomicAdd(&sacc[g * NCLS + cc], out2[(size_t)n * NCLS + cc]);
    }
    __syncthreads();
    for (int i = threadIdx.x; i < NGRP * NCLS; i += 256)
        if (sacc[i] != 0.f) atomicAdd(&poolS[i], sacc[i]);
    if (threadIdx.x < NGRP && scnt[threadIdx.x] != 0.f)
        atomicAdd(&poolC[threadIdx.x], scnt[threadIdx.x]);
}

__global__ void k_final(const float* __restrict__ poolS,
                        const float* __restrict__ poolC, float* __restrict__ out) {
    int g = threadIdx.x;
    if (g >= NGRP) return;
    float inv = 1.f / fmaxf(poolC[g], 1.f);
    float v[NCLS];
    float m = -1e30f;
#pragma unroll
    for (int c = 0; c < NCLS; ++c) {
        v[c] = poolS[g * NCLS + c] * inv;
        m = fmaxf(m, v[c]);
    }
    float s = 0.f;
#pragma unroll
    for (int c = 0; c < NCLS; ++c) s += expf(v[c] - m);
    float lse = m + logf(s);
#pragma unroll
    for (int c = 0; c < NCLS; ++c) out[g * NCLS + c] = v[c] - lse;
}

extern "C" void kernel_launch(void* const* d_in, const int* in_sizes, int n_in,
                              void* d_out, int out_size, void* d_ws, size_t ws_size,
                              hipStream_t stream) {
    const float* x    = (const float*)d_in[0];
    const int*   ei   = (const int*)d_in[1];
    const int*   batch = (const int*)d_in[2];
    const float* W1   = (const float*)d_in[3];
    const float* a1s  = (const float*)d_in[4];
    const float* a1d  = (const float*)d_in[5];
    const float* b1   = (const float*)d_in[6];
    const float* W2   = (const float*)d_in[7];
    const float* a2s  = (const float*)d_in[8];
    const float* a2d  = (const float*)d_in[9];
    const float* b2   = (const float*)d_in[10];
    float* out = (float*)d_out;

    float* f = (float*)d_ws;
    float* al1s_ = f;  f += (size_t)N_NODES * NH;
    float* al1d_ = f;  f += (size_t)N_NODES * NH;
    float* xp2   = f;  f += (size_t)N_NODES * NCLS;
    float* al2s_ = f;  f += N_NODES;
    float* al2d_ = f;  f += N_NODES;
    float* out2  = f;  f += (size_t)N_NODES * NCLS;
    float* poolS = f;  f += NGRP * NCLS;
    float* poolC = f;  f += NGRP;
    unsigned short* xp1b = (unsigned short*)f;
    unsigned short* h1b  = xp1b + (size_t)N_NODES * D1;
    int* cnt    = (int*)(h1b + (size_t)N_NODES * D1);
    int* rowptr = cnt + N_NODES;
    int* cursor = rowptr + N_NODES;
    int* esrc   = cursor + N_NODES;
    int* bsums  = esrc + E_TOT;

    const int NB_N = (N_NODES + 255) / 256;   // 196

    k_init<<<NB_N, 256, 0, stream>>>(cnt, poolS, poolC);
    k_gemm1<<<(N_NODES + 63) / 64, 256, 0, stream>>>(x, W1, a1s, a1d, xp1b, al1s_, al1d_);
    k_hist<<<(N_EDGES + 255) / 256, 256, 0, stream>>>(ei, cnt);
    k_scan1<<<NB_N, 256, 0, stream>>>(cnt, rowptr, bsums);
    k_scan2<<<1, 256, 0, stream>>>(bsums, NB_N);
    k_scan3<<<NB_N, 256, 0, stream>>>(rowptr, bsums, cursor);
    k_scatter<<<(E_TOT + 255) / 256, 256, 0, stream>>>(ei, cursor, esrc);
    k_att1<<<(N_NODES + 3) / 4, 256, 0, stream>>>(xp1b, al1s_, al1d_, b1, rowptr, cnt, esrc, h1b);
    k_gemm2<<<NB_N, 256, 0, stream>>>(h1b, W2, a2s, a2d, xp2, al2s_, al2d_);
    k_att2<<<(N_NODES + 3) / 4, 256, 0, stream>>>(xp2, al2s_, al2d_, b2, rowptr, cnt, esrc, out2);
    k_pool<<<NB_N, 256, 0, stream>>>(out2, batch, poolS, poolC);
    k_final<<<1, 64, 0, stream>>>(poolS, poolC, out);
}